// Round 10
// baseline (217.451 us; speedup 1.0000x reference)
//
#include <hip/hip_runtime.h>
#include <math.h>

// LDDMM variational RHS, Gaussian kernel sigma=0.1, B=1, N=8192, D=3.
// out[0:N*3]     = dmom_i = (1/sig^2) * (x_i * sum_j W_ij - sum_j W_ij x_j)
// out[N*3:2*N*3] = dcp_i  = sum_j K_ij p_j
// K_ij = exp(-|x_i-x_j|^2/(2 sig^2)), W_ij = K_ij*(p_i.p_j), p=clamp(mom,-1,1)
//
// R10 model (fits R2..R9): pair kernel is LDS-return-bus bound -- total
// ds_read_b128 count was invariant (1.05M = 49k cy/CU ~= 33us at the
// observed ~1.4-1.5GHz effective clock) across R2/R3/R6/R8/R9, and R9's
// direct counters show VALU-issue is only ~16.5us (VALUBusy 33.6% x 49.2us)
// with the rest stall. R7 cut LDS 4x but fell to 8 waves/CU (latency-bound).
// R10 = R7's LDS amortization at R6's occupancy: MI=4 v2f (8 i/thread),
// JC=256 -> 1024 blocks = 4 blk/CU = 16 waves/CU. LDS 12.3k cy/CU (~8us)
// < VALU 22.5k cy/SIMD (~15us) -> VALU-bound. Two-phase, SoA ws (6 planes,
// wsum dropped: wsum = p_i . dcp, linear, reconstructed in reduce).
// Harness's 256MiB d_ws 0xAA re-poison (~44-48us fill) is a fixed tax.

#define NPTS 8192
#define N3   (NPTS * 3)
#define BI   256
#define MI   4                        // v2f groups per thread = 8 i-points
#define PPT  (MI * 2)
#define IBLK (NPTS / (BI * PPT))      // 4 i-blocks
#define JC   256                      // j-chunks
#define JLEN (NPTS / JC)              // 32 j's per chunk
#define PLSZ ((size_t)JC * NPTS)      // plane size (floats)

// exp(-d2/(2*0.1^2)) = exp2(d2 * (-50*log2(e)))
#define COEF    (-72.134752044448170f)
#define M2COEF  (144.269504088896340f)     // -2*COEF
#define UNSC100 (0.69314718055994531f)     // 100 / M2COEF

#define WS_NEEDED ((size_t)6 * PLSZ * sizeof(float))  // 50.3 MB

typedef float v2f __attribute__((ext_vector_type(2)));

__device__ __forceinline__ v2f vsplat(float s) { v2f r; r.x = s; r.y = s; return r; }

__device__ __forceinline__ v2f pkfma(v2f a, v2f b, v2f c) {
#if __has_builtin(__builtin_elementwise_fma)
    return __builtin_elementwise_fma(a, b, c);
#else
    v2f r; r.x = fmaf(a.x, b.x, c.x); r.y = fmaf(a.y, b.y, c.y); return r;
#endif
}

__device__ __forceinline__ float fast_exp2(float x) {
#if __has_builtin(__builtin_amdgcn_exp2f)
    return __builtin_amdgcn_exp2f(x);
#else
    return exp2f(x);
#endif
}

__device__ __forceinline__ float clamp1(float v) {
    return fminf(fmaxf(v, -1.0f), 1.0f);
}

// ws: 6 SoA planes of [JC][NPTS]: 0..2 = dcp, 3..5 = wxs (M2COEF-scaled wx)
__global__ __launch_bounds__(BI, 4) void lddmm_partial(const float* __restrict__ mom,
                                                       const float* __restrict__ cp,
                                                       float* __restrict__ ws) {
    const int ib = (int)blockIdx.x / JC;
    const int jc = (int)blockIdx.x % JC;
    const int t  = (int)threadIdx.x;
    const int i0 = ib * (BI * PPT) + t;   // 8 i's/thread, stride BI
                                          // v2f m: .x = i0+2m*BI, .y = i0+(2m+1)*BI

    v2f xi0[MI], xi1[MI], xi2[MI], ci[MI], pi0[MI], pi1[MI], pi2[MI];
#pragma unroll
    for (int m = 0; m < MI; ++m) {
        const int ia  = i0 + (2 * m) * BI;
        const int ib2 = i0 + (2 * m + 1) * BI;
        const float a0 = cp[ia * 3 + 0], a1 = cp[ia * 3 + 1], a2 = cp[ia * 3 + 2];
        const float b0 = cp[ib2 * 3 + 0], b1 = cp[ib2 * 3 + 1], b2 = cp[ib2 * 3 + 2];
        xi0[m].x = a0; xi0[m].y = b0;
        xi1[m].x = a1; xi1[m].y = b1;
        xi2[m].x = a2; xi2[m].y = b2;
        ci[m].x = COEF * (a0 * a0 + a1 * a1 + a2 * a2);
        ci[m].y = COEF * (b0 * b0 + b1 * b1 + b2 * b2);
        pi0[m].x = clamp1(mom[ia * 3 + 0]); pi0[m].y = clamp1(mom[ib2 * 3 + 0]);
        pi1[m].x = clamp1(mom[ia * 3 + 1]); pi1[m].y = clamp1(mom[ib2 * 3 + 1]);
        pi2[m].x = clamp1(mom[ia * 3 + 2]); pi2[m].y = clamp1(mom[ib2 * 3 + 2]);
    }

    // Stage j-chunk: shx = {M2COEF*xj, COEF*|xj|^2}, shp = {pj clamped, 0}
    __shared__ float4 shx[JLEN];
    __shared__ float4 shp[JLEN];
    if (t < JLEN) {
        const int j = jc * JLEN + t;
        const float x0 = cp[j * 3 + 0], x1 = cp[j * 3 + 1], x2 = cp[j * 3 + 2];
        shx[t] = make_float4(M2COEF * x0, M2COEF * x1, M2COEF * x2,
                             COEF * (x0 * x0 + x1 * x1 + x2 * x2));
        shp[t] = make_float4(clamp1(mom[j * 3 + 0]), clamp1(mom[j * 3 + 1]),
                             clamp1(mom[j * 3 + 2]), 0.0f);
    }
    __syncthreads();

    v2f dcp0[MI], dcp1[MI], dcp2[MI], wx0[MI], wx1[MI], wx2[MI];
#pragma unroll
    for (int m = 0; m < MI; ++m) {
        dcp0[m] = vsplat(0.f); dcp1[m] = vsplat(0.f); dcp2[m] = vsplat(0.f);
        wx0[m] = vsplat(0.f); wx1[m] = vsplat(0.f); wx2[m] = vsplat(0.f);
    }

#pragma unroll 4
    for (int jj = 0; jj < JLEN; ++jj) {
        const float4 xj = shx[jj];   // wave-uniform -> LDS broadcast
        const float4 pj = shp[jj];
        const v2f sx0 = vsplat(xj.x), sx1 = vsplat(xj.y), sx2 = vsplat(xj.z);
        const v2f scj = vsplat(xj.w);
        const v2f sp0 = vsplat(pj.x), sp1 = vsplat(pj.y), sp2 = vsplat(pj.z);
#pragma unroll
        for (int m = 0; m < MI; ++m) {
            v2f arg = ci[m] + scj;               // 1 pk_add + 3 pk_fma
            arg = pkfma(xi2[m], sx2, arg);
            arg = pkfma(xi1[m], sx1, arg);
            arg = pkfma(xi0[m], sx0, arg);
            v2f K;                               // 2 trans
            K.x = fast_exp2(arg.x);
            K.y = fast_exp2(arg.y);
            v2f pd = pi0[m] * sp0;               // 1 pk_mul + 2 pk_fma
            pd = pkfma(pi1[m], sp1, pd);
            pd = pkfma(pi2[m], sp2, pd);
            const v2f W = K * pd;                // 1 pk_mul
            dcp0[m] = pkfma(K, sp0, dcp0[m]);    // 3 pk_fma
            dcp1[m] = pkfma(K, sp1, dcp1[m]);
            dcp2[m] = pkfma(K, sp2, dcp2[m]);
            wx0[m] = pkfma(W, sx0, wx0[m]);      // 3 pk_fma (M2COEF-scaled)
            wx1[m] = pkfma(W, sx1, wx1[m]);
            wx2[m] = pkfma(W, sx2, wx2[m]);
            // no wsum accumulate: wsum = p_i . dcp (reconstructed in reduce)
        }
    }

    // SoA stores: 6 planes x 8 i's, coalesced (t contiguous -> i contiguous)
    const size_t rbase = (size_t)jc * NPTS;
#pragma unroll
    for (int m = 0; m < MI; ++m) {
        const size_t ra = rbase + (size_t)(i0 + (2 * m) * BI);
        const size_t rb = rbase + (size_t)(i0 + (2 * m + 1) * BI);
        ws[0 * PLSZ + ra] = dcp0[m].x;  ws[0 * PLSZ + rb] = dcp0[m].y;
        ws[1 * PLSZ + ra] = dcp1[m].x;  ws[1 * PLSZ + rb] = dcp1[m].y;
        ws[2 * PLSZ + ra] = dcp2[m].x;  ws[2 * PLSZ + rb] = dcp2[m].y;
        ws[3 * PLSZ + ra] = wx0[m].x;   ws[3 * PLSZ + rb] = wx0[m].y;
        ws[4 * PLSZ + ra] = wx1[m].x;   ws[4 * PLSZ + rb] = wx1[m].y;
        ws[5 * PLSZ + ra] = wx2[m].x;   ws[5 * PLSZ + rb] = wx2[m].y;
    }
}

// Reduce: grid (NPTS/256, 8). Block (x=i-block, y=cpart of 32 chunks).
// Each thread sums 32 chunks of 6 planes for one i, applies the (linear)
// dmom formula to its partial, atomicAdds 6 outputs (8-way contention).
#define CPART 8
#define CPL   (JC / CPART)   // 32 chunks per part
__global__ __launch_bounds__(256) void lddmm_reduce(const float* __restrict__ ws,
                                                    const float* __restrict__ mom,
                                                    const float* __restrict__ cp,
                                                    float* __restrict__ out) {
    const int i  = (int)blockIdx.x * 256 + (int)threadIdx.x;
    const int c0 = (int)blockIdx.y * CPL;

    float d0 = 0.f, d1 = 0.f, d2 = 0.f, w0 = 0.f, w1 = 0.f, w2 = 0.f;
#pragma unroll 8
    for (int c = c0; c < c0 + CPL; ++c) {
        const size_t r = (size_t)c * NPTS + i;
        d0 += ws[0 * PLSZ + r];
        d1 += ws[1 * PLSZ + r];
        d2 += ws[2 * PLSZ + r];
        w0 += ws[3 * PLSZ + r];
        w1 += ws[4 * PLSZ + r];
        w2 += ws[5 * PLSZ + r];
    }
    const float p0 = clamp1(mom[i * 3 + 0]);
    const float p1 = clamp1(mom[i * 3 + 1]);
    const float p2 = clamp1(mom[i * 3 + 2]);
    const float x0 = cp[i * 3 + 0];
    const float x1 = cp[i * 3 + 1];
    const float x2 = cp[i * 3 + 2];
    float wsum = p0 * d0;
    wsum = fmaf(p1, d1, wsum);
    wsum = fmaf(p2, d2, wsum);
    atomicAdd(&out[i * 3 + 0], fmaf(100.0f * x0, wsum, -UNSC100 * w0));
    atomicAdd(&out[i * 3 + 1], fmaf(100.0f * x1, wsum, -UNSC100 * w1));
    atomicAdd(&out[i * 3 + 2], fmaf(100.0f * x2, wsum, -UNSC100 * w2));
    atomicAdd(&out[N3 + i * 3 + 0], d0);
    atomicAdd(&out[N3 + i * 3 + 1], d1);
    atomicAdd(&out[N3 + i * 3 + 2], d2);
}

// ---- fallback (atomics into d_out) if ws_size < WS_NEEDED ----
#define FJC   32
#define FJLEN (NPTS / FJC)
__global__ __launch_bounds__(BI) void lddmm_pairs_atomic(const float* __restrict__ mom,
                                                         const float* __restrict__ cp,
                                                         float* __restrict__ out) {
    const int ib = (int)blockIdx.x / FJC;
    const int jc = (int)blockIdx.x % FJC;
    const int t  = (int)threadIdx.x;
    const int i  = ib * BI + t;

    const float xi0 = cp[i * 3 + 0], xi1 = cp[i * 3 + 1], xi2 = cp[i * 3 + 2];
    const float pi0 = clamp1(mom[i * 3 + 0]), pi1 = clamp1(mom[i * 3 + 1]),
                pi2 = clamp1(mom[i * 3 + 2]);

    __shared__ float4 shx[FJLEN];
    __shared__ float4 shp[FJLEN];
    {
        const int j = jc * FJLEN + t;
        shx[t] = make_float4(cp[j * 3 + 0], cp[j * 3 + 1], cp[j * 3 + 2], 0.0f);
        shp[t] = make_float4(clamp1(mom[j * 3 + 0]), clamp1(mom[j * 3 + 1]),
                             clamp1(mom[j * 3 + 2]), 0.0f);
    }
    __syncthreads();

    float dcp0 = 0.f, dcp1 = 0.f, dcp2 = 0.f, wsum = 0.f, wx0 = 0.f, wx1 = 0.f, wx2 = 0.f;
#pragma unroll 4
    for (int jj = 0; jj < FJLEN; ++jj) {
        const float4 xj = shx[jj];
        const float4 pj = shp[jj];
        const float dx0 = xi0 - xj.x, dx1 = xi1 - xj.y, dx2 = xi2 - xj.z;
        const float d2  = dx0 * dx0 + dx1 * dx1 + dx2 * dx2;
        const float K   = fast_exp2(d2 * COEF);
        const float pd  = pi0 * pj.x + pi1 * pj.y + pi2 * pj.z;
        const float W   = K * pd;
        dcp0 += K * pj.x; dcp1 += K * pj.y; dcp2 += K * pj.z;
        wsum += W;
        wx0 += W * xj.x; wx1 += W * xj.y; wx2 += W * xj.z;
    }
    atomicAdd(&out[i * 3 + 0], 100.0f * (xi0 * wsum - wx0));
    atomicAdd(&out[i * 3 + 1], 100.0f * (xi1 * wsum - wx1));
    atomicAdd(&out[i * 3 + 2], 100.0f * (xi2 * wsum - wx2));
    atomicAdd(&out[N3 + i * 3 + 0], dcp0);
    atomicAdd(&out[N3 + i * 3 + 1], dcp1);
    atomicAdd(&out[N3 + i * 3 + 2], dcp2);
}

extern "C" void kernel_launch(void* const* d_in, const int* in_sizes, int n_in,
                              void* d_out, int out_size, void* d_ws, size_t ws_size,
                              hipStream_t stream) {
    const float* mom = (const float*)d_in[0];
    const float* cp  = (const float*)d_in[1];
    float* out = (float*)d_out;

    // out is poisoned 0xAA before every launch; reduce accumulates atomically.
    hipMemsetAsync(out, 0, (size_t)out_size * sizeof(float), stream);

    if (ws_size >= WS_NEEDED) {
        float* ws = (float*)d_ws;
        hipLaunchKernelGGL(lddmm_partial, dim3(IBLK * JC), dim3(BI), 0, stream, mom, cp, ws);
        hipLaunchKernelGGL(lddmm_reduce, dim3(NPTS / 256, CPART), dim3(256), 0, stream,
                           ws, mom, cp, out);
    } else {
        hipLaunchKernelGGL(lddmm_pairs_atomic, dim3((NPTS / BI) * FJC), dim3(BI), 0, stream,
                           mom, cp, out);
    }
}

// Round 11
// 96.353 us; speedup vs baseline: 2.2568x; 2.2568x over previous
//
#include <hip/hip_runtime.h>
#include <math.h>

// LDDMM variational RHS, Gaussian kernel sigma=0.1, B=1, N=8192, D=3.
// out[0:N*3]     = dmom_i = (1/sig^2) * (x_i * sum_j W_ij - sum_j W_ij x_j)
// out[N*3:2*N*3] = dcp_i  = sum_j K_ij p_j
// K_ij = exp(-|x_i-x_j|^2/(2 sig^2)), W_ij = K_ij*(p_i.p_j), p=clamp(mom,-1,1)
//
// R11. Consolidated model (R2..R10): effective SCLK parks at ~870 MHz during
// this memory-fill-dominated timed loop (R9: VALU-issue 16.5us over 14.3k
// cy/SIMD). Pair-loop issue floor = 14.3k VALU + 8.2k trans cy/SIMD ~ 26us;
// all configs measure ~33us (~25% stall). R10's scalar 6-plane SoA stores
// caused 580MB RFO/write-amplified HBM traffic -- ws stores must stay
// float4. R11 = best-known structure (R6/R8) + two untested levers:
//   - wsum identity (wsum = p_i . dcp, R9-proven): 14 pk-ops/m-group
//   - 32 waves/CU: 2 packed i/thread, JC=128 -> 2048 blocks = 8 blk/CU,
//     double R6's occupancy, to attack the stall fraction.
// Harness's 256MiB d_ws 0xAA re-poison (~44-48us fill) is a fixed tax.

#define NPTS 8192
#define N3   (NPTS * 3)
#define BI   256
#define IBLK (NPTS / (BI * 2))       // 16 i-blocks (2 packed i's per thread)
#define JC   128                     // j-chunks
#define JLEN (NPTS / JC)             // 64 j's per chunk

// exp(-d2/(2*0.1^2)) = exp2(d2 * (-50*log2(e)))
#define COEF    (-72.134752044448170f)
#define M2COEF  (144.269504088896340f)     // -2*COEF
#define UNSC100 (0.69314718055994531f)     // 100 / M2COEF

#define WS_NEEDED ((size_t)JC * NPTS * 8 * sizeof(float))  // 33.5 MB

typedef float v2f __attribute__((ext_vector_type(2)));

__device__ __forceinline__ v2f vsplat(float s) { v2f r; r.x = s; r.y = s; return r; }

__device__ __forceinline__ v2f pkfma(v2f a, v2f b, v2f c) {
#if __has_builtin(__builtin_elementwise_fma)
    return __builtin_elementwise_fma(a, b, c);
#else
    v2f r; r.x = fmaf(a.x, b.x, c.x); r.y = fmaf(a.y, b.y, c.y); return r;
#endif
}

__device__ __forceinline__ float fast_exp2(float x) {
#if __has_builtin(__builtin_amdgcn_exp2f)
    return __builtin_amdgcn_exp2f(x);
#else
    return exp2f(x);
#endif
}

__device__ __forceinline__ float clamp1(float v) {
    return fminf(fmaxf(v, -1.0f), 1.0f);
}

// ws layout (R8-proven): ws[((c*NPTS)+i)*8 + k]
//   k=0..3: dcp0,dcp1,dcp2,<unused>   k=4..7: wxs0,wxs1,wxs2,0 (wxs=M2COEF*wx)
__global__ __launch_bounds__(BI, 4) void lddmm_partial(const float* __restrict__ mom,
                                                       const float* __restrict__ cp,
                                                       float* __restrict__ ws) {
    const int ib = (int)blockIdx.x / JC;
    const int jc = (int)blockIdx.x % JC;
    const int t  = (int)threadIdx.x;
    const int i0 = ib * (BI * 2) + t;     // packed .x
    const int i1 = i0 + BI;               // packed .y

    v2f xi0, xi1, xi2, ci, pi0, pi1, pi2;
    {
        const float a0 = cp[i0 * 3 + 0], a1 = cp[i0 * 3 + 1], a2 = cp[i0 * 3 + 2];
        const float b0 = cp[i1 * 3 + 0], b1 = cp[i1 * 3 + 1], b2 = cp[i1 * 3 + 2];
        xi0.x = a0; xi0.y = b0;
        xi1.x = a1; xi1.y = b1;
        xi2.x = a2; xi2.y = b2;
        ci.x = COEF * (a0 * a0 + a1 * a1 + a2 * a2);
        ci.y = COEF * (b0 * b0 + b1 * b1 + b2 * b2);
        pi0.x = clamp1(mom[i0 * 3 + 0]); pi0.y = clamp1(mom[i1 * 3 + 0]);
        pi1.x = clamp1(mom[i0 * 3 + 1]); pi1.y = clamp1(mom[i1 * 3 + 1]);
        pi2.x = clamp1(mom[i0 * 3 + 2]); pi2.y = clamp1(mom[i1 * 3 + 2]);
    }

    // Stage j-chunk: shx = {M2COEF*xj, COEF*|xj|^2}, shp = {pj clamped, 0}
    __shared__ float4 shx[JLEN];
    __shared__ float4 shp[JLEN];
    if (t < JLEN) {
        const int j = jc * JLEN + t;
        const float x0 = cp[j * 3 + 0], x1 = cp[j * 3 + 1], x2 = cp[j * 3 + 2];
        shx[t] = make_float4(M2COEF * x0, M2COEF * x1, M2COEF * x2,
                             COEF * (x0 * x0 + x1 * x1 + x2 * x2));
        shp[t] = make_float4(clamp1(mom[j * 3 + 0]), clamp1(mom[j * 3 + 1]),
                             clamp1(mom[j * 3 + 2]), 0.0f);
    }
    __syncthreads();

    v2f dcp0 = vsplat(0.f), dcp1 = vsplat(0.f), dcp2 = vsplat(0.f);
    v2f wx0 = vsplat(0.f), wx1 = vsplat(0.f), wx2 = vsplat(0.f);

#pragma unroll 8
    for (int jj = 0; jj < JLEN; ++jj) {
        const float4 xj = shx[jj];   // wave-uniform -> LDS broadcast
        const float4 pj = shp[jj];
        v2f arg = ci + vsplat(xj.w);             // 1 pk_add + 3 pk_fma
        arg = pkfma(xi2, vsplat(xj.z), arg);
        arg = pkfma(xi1, vsplat(xj.y), arg);
        arg = pkfma(xi0, vsplat(xj.x), arg);
        v2f K;                                   // 2 trans
        K.x = fast_exp2(arg.x);
        K.y = fast_exp2(arg.y);
        v2f pd = pi0 * vsplat(pj.x);             // 1 pk_mul + 2 pk_fma
        pd = pkfma(pi1, vsplat(pj.y), pd);
        pd = pkfma(pi2, vsplat(pj.z), pd);
        const v2f W = K * pd;                    // 1 pk_mul
        dcp0 = pkfma(K, vsplat(pj.x), dcp0);     // 3 pk_fma
        dcp1 = pkfma(K, vsplat(pj.y), dcp1);
        dcp2 = pkfma(K, vsplat(pj.z), dcp2);
        wx0 = pkfma(W, vsplat(xj.x), wx0);       // 3 pk_fma (M2COEF-scaled)
        wx1 = pkfma(W, vsplat(xj.y), wx1);
        wx2 = pkfma(W, vsplat(xj.z), wx2);
        // no wsum accumulate: wsum_chunk = p_i . dcp_chunk (identity)
    }

    float4* oa = (float4*)(ws + ((size_t)(jc * NPTS) + i0) * 8);
    oa[0] = make_float4(dcp0.x, dcp1.x, dcp2.x, 0.0f);
    oa[1] = make_float4(wx0.x, wx1.x, wx2.x, 0.0f);
    float4* ob = (float4*)(ws + ((size_t)(jc * NPTS) + i1) * 8);
    ob[0] = make_float4(dcp0.y, dcp1.y, dcp2.y, 0.0f);
    ob[1] = make_float4(wx0.y, wx1.y, wx2.y, 0.0f);
}

// 4 threads per i: sub=(cpart,half). Each sums JC/2 chunks of one float4,
// xor-2 combines chunk halves. half0 holds dcp, half1 holds wxs.
// wsum = p_i . dcp (identity); xor-1 hands it from half0 to half1.
__global__ __launch_bounds__(256) void lddmm_reduce(const float* __restrict__ ws,
                                                    const float* __restrict__ mom,
                                                    const float* __restrict__ cp,
                                                    float* __restrict__ out) {
    const int tid   = (int)blockIdx.x * 256 + (int)threadIdx.x;
    const int i     = tid >> 2;
    const int sub   = tid & 3;
    const int half  = sub & 1;
    const int cpart = sub >> 1;

    float4 acc = make_float4(0.f, 0.f, 0.f, 0.f);
    const int c0 = cpart * (JC / 2);
#pragma unroll 4
    for (int c = c0; c < c0 + JC / 2; ++c) {
        const float4 v = ((const float4*)(ws + ((size_t)(c * NPTS) + i) * 8))[half];
        acc.x += v.x; acc.y += v.y; acc.z += v.z;
    }
    // combine chunk halves (lanes differing in bit 1)
    acc.x += __shfl_xor(acc.x, 2);
    acc.y += __shfl_xor(acc.y, 2);
    acc.z += __shfl_xor(acc.z, 2);

    const float p0 = clamp1(mom[i * 3 + 0]);
    const float p1 = clamp1(mom[i * 3 + 1]);
    const float p2 = clamp1(mom[i * 3 + 2]);
    // half0's acc = dcp; compute wsum there and hand to half1
    float wsum_loc = p0 * acc.x;
    wsum_loc = fmaf(p1, acc.y, wsum_loc);
    wsum_loc = fmaf(p2, acc.z, wsum_loc);
    const float wsum = __shfl_xor(wsum_loc, 1);

    if (sub == 0) {
        out[N3 + i * 3 + 0] = acc.x;
        out[N3 + i * 3 + 1] = acc.y;
        out[N3 + i * 3 + 2] = acc.z;
    } else if (sub == 1) {
        const float x0 = cp[i * 3 + 0];
        const float x1 = cp[i * 3 + 1];
        const float x2 = cp[i * 3 + 2];
        out[i * 3 + 0] = fmaf(100.0f * x0, wsum, -UNSC100 * acc.x);
        out[i * 3 + 1] = fmaf(100.0f * x1, wsum, -UNSC100 * acc.y);
        out[i * 3 + 2] = fmaf(100.0f * x2, wsum, -UNSC100 * acc.z);
    }
}

// ---- fallback (atomics into d_out) if ws_size < WS_NEEDED ----
#define FJC   32
#define FJLEN (NPTS / FJC)
__global__ __launch_bounds__(BI) void lddmm_pairs_atomic(const float* __restrict__ mom,
                                                         const float* __restrict__ cp,
                                                         float* __restrict__ out) {
    const int ib = (int)blockIdx.x / FJC;
    const int jc = (int)blockIdx.x % FJC;
    const int t  = (int)threadIdx.x;
    const int i  = ib * BI + t;

    const float xi0 = cp[i * 3 + 0], xi1 = cp[i * 3 + 1], xi2 = cp[i * 3 + 2];
    const float pi0 = clamp1(mom[i * 3 + 0]), pi1 = clamp1(mom[i * 3 + 1]),
                pi2 = clamp1(mom[i * 3 + 2]);

    __shared__ float4 shx[FJLEN];
    __shared__ float4 shp[FJLEN];
    {
        const int j = jc * FJLEN + t;
        shx[t] = make_float4(cp[j * 3 + 0], cp[j * 3 + 1], cp[j * 3 + 2], 0.0f);
        shp[t] = make_float4(clamp1(mom[j * 3 + 0]), clamp1(mom[j * 3 + 1]),
                             clamp1(mom[j * 3 + 2]), 0.0f);
    }
    __syncthreads();

    float dcp0 = 0.f, dcp1 = 0.f, dcp2 = 0.f, wsum = 0.f, wx0 = 0.f, wx1 = 0.f, wx2 = 0.f;
#pragma unroll 4
    for (int jj = 0; jj < FJLEN; ++jj) {
        const float4 xj = shx[jj];
        const float4 pj = shp[jj];
        const float dx0 = xi0 - xj.x, dx1 = xi1 - xj.y, dx2 = xi2 - xj.z;
        const float d2  = dx0 * dx0 + dx1 * dx1 + dx2 * dx2;
        const float K   = fast_exp2(d2 * COEF);
        const float pd  = pi0 * pj.x + pi1 * pj.y + pi2 * pj.z;
        const float W   = K * pd;
        dcp0 += K * pj.x; dcp1 += K * pj.y; dcp2 += K * pj.z;
        wsum += W;
        wx0 += W * xj.x; wx1 += W * xj.y; wx2 += W * xj.z;
    }
    atomicAdd(&out[i * 3 + 0], 100.0f * (xi0 * wsum - wx0));
    atomicAdd(&out[i * 3 + 1], 100.0f * (xi1 * wsum - wx1));
    atomicAdd(&out[i * 3 + 2], 100.0f * (xi2 * wsum - wx2));
    atomicAdd(&out[N3 + i * 3 + 0], dcp0);
    atomicAdd(&out[N3 + i * 3 + 1], dcp1);
    atomicAdd(&out[N3 + i * 3 + 2], dcp2);
}

extern "C" void kernel_launch(void* const* d_in, const int* in_sizes, int n_in,
                              void* d_out, int out_size, void* d_ws, size_t ws_size,
                              hipStream_t stream) {
    const float* mom = (const float*)d_in[0];
    const float* cp  = (const float*)d_in[1];
    float* out = (float*)d_out;

    if (ws_size >= WS_NEEDED) {
        float* ws = (float*)d_ws;
        hipLaunchKernelGGL(lddmm_partial, dim3(IBLK * JC), dim3(BI), 0, stream, mom, cp, ws);
        hipLaunchKernelGGL(lddmm_reduce, dim3(NPTS * 4 / 256), dim3(256), 0, stream,
                           ws, mom, cp, out);
    } else {
        hipMemsetAsync(out, 0, (size_t)out_size * sizeof(float), stream);
        hipLaunchKernelGGL(lddmm_pairs_atomic, dim3((NPTS / BI) * FJC), dim3(BI), 0, stream,
                           mom, cp, out);
    }
}